// Round 11
// baseline (120.937 us; speedup 1.0000x reference)
//
#include <hip/hip_runtime.h>
#include <hip/hip_bf16.h>
#include <math.h>

// Problem constants (from reference)
#define BATCH   2
#define SEQ     512     // N
#define DIN     512
#define DM      256     // d_model

#define LOG2E2  2.88539008177792681f   // 2*log2(e)

#if __has_builtin(__builtin_amdgcn_exp2f)
#define EXP2(x) __builtin_amdgcn_exp2f(x)
#else
#define EXP2(x) exp2f(x)
#endif
#if __has_builtin(__builtin_amdgcn_rcpf)
#define RCP(x) __builtin_amdgcn_rcpf(x)
#else
#define RCP(x) (1.0f / (x))
#endif

// tanh(t) with targ = 2*log2(e)*t: tanh = 1 - 2/(1 + exp2(targ)); overflow-safe.
__device__ __forceinline__ float tanh_from_scaled(float targ) {
    return fmaf(-2.0f, RCP(1.0f + EXP2(targ)), 1.0f);
}

// ---------------- Kernel 1: EB2 pairs + EA rows + h = tanh(x@Wx+bx) ----------------
// (unchanged from r10 — works, not the bottleneck)
__global__ __launch_bounds__(512) void prep_k(
    const float* __restrict__ pos,  // [B, N, 4]
    const float* __restrict__ Wp,   // [4, DM]
    const float* __restrict__ bp,   // [DM]
    const float* __restrict__ x,    // [B*N, DIN]
    const float* __restrict__ Wx,   // [DIN, DM]
    const float* __restrict__ bx,   // [DM]
    float* __restrict__ EA,         // [B*N, DM]
    float2* __restrict__ EB2,       // [B][128][SEQ] float2
    float* __restrict__ h)          // [B*N, DM]
{
    const int tid = threadIdx.x;

    if (blockIdx.x < 256) {
        // ---- EB2 part: block = (b, tg); d-pair (2tg, 2tg+1); thread = j ----
        const int b  = blockIdx.x >> 7;
        const int tg = blockIdx.x & 127;
        const int d0 = 2 * tg, d1 = d0 + 1;

        const float4 p = ((const float4*)pos)[b * SEQ + tid];   // coalesced 16B
        const float P0 = fmaf(p.x, Wp[d0], fmaf(p.y, Wp[DM + d0],
                         fmaf(p.z, Wp[2*DM + d0], p.w * Wp[3*DM + d0])));
        const float P1 = fmaf(p.x, Wp[d1], fmaf(p.y, Wp[DM + d1],
                         fmaf(p.z, Wp[2*DM + d1], p.w * Wp[3*DM + d1])));
        EB2[((size_t)(b * 128 + tg)) * SEQ + tid] =
            make_float2(EXP2(-LOG2E2 * P0), EXP2(-LOG2E2 * P1));   // coalesced 8B
        return;
    }

    // ---- h + EA part: rows row0, row0+1 ----
    __shared__ float4 s_x[2][DIN/4];       // 4 KB
    __shared__ float4 s_part[2][7][64];    // 14 KB

    const int row0 = (blockIdx.x - 256) * 2;

    // EA (independent of h)
    {
        const int r2  = __builtin_amdgcn_readfirstlane(tid >> 8);   // 0/1
        const int d   = tid & 255;
        const int row = row0 + r2;
        const float4 p = ((const float4*)pos)[row];   // uniform -> s_load
        const float P = fmaf(p.x, Wp[d],
                        fmaf(p.y, Wp[DM + d],
                        fmaf(p.z, Wp[2*DM + d],
                             p.w * Wp[3*DM + d])));
        EA[(size_t)row * DM + d] = EXP2(LOG2E2 * (P + bp[d]));   // coalesced
    }

    // stage both x rows (coalesced float4)
    if (tid < 256) {
        const int r   = tid >> 7;
        const int idx = tid & 127;
        s_x[r][idx] = ((const float4*)(x + (size_t)(row0 + r) * DIN))[idx];
    }
    __syncthreads();

    const int w = tid >> 6;        // k-eighth 0..7
    const int l = tid & 63;        // lane -> cols 4l..4l+3

    float4 acc0 = make_float4(0.f, 0.f, 0.f, 0.f);
    float4 acc1 = make_float4(0.f, 0.f, 0.f, 0.f);
    const float* __restrict__ wxp = Wx + 4 * l;

    #pragma unroll 2
    for (int k4 = 0; k4 < 16; k4++) {
        const int kk = w * 16 + k4;
        const float4 xv0 = s_x[0][kk];                    // ds_read_b128 broadcast
        const float4 xv1 = s_x[1][kk];
        const float4 w0 = *(const float4*)(wxp + (size_t)(4*kk + 0) * DM);
        const float4 w1 = *(const float4*)(wxp + (size_t)(4*kk + 1) * DM);
        const float4 w2 = *(const float4*)(wxp + (size_t)(4*kk + 2) * DM);
        const float4 w3 = *(const float4*)(wxp + (size_t)(4*kk + 3) * DM);
        acc0.x = fmaf(xv0.x, w0.x, acc0.x); acc0.y = fmaf(xv0.x, w0.y, acc0.y);
        acc0.z = fmaf(xv0.x, w0.z, acc0.z); acc0.w = fmaf(xv0.x, w0.w, acc0.w);
        acc0.x = fmaf(xv0.y, w1.x, acc0.x); acc0.y = fmaf(xv0.y, w1.y, acc0.y);
        acc0.z = fmaf(xv0.y, w1.z, acc0.z); acc0.w = fmaf(xv0.y, w1.w, acc0.w);
        acc0.x = fmaf(xv0.z, w2.x, acc0.x); acc0.y = fmaf(xv0.z, w2.y, acc0.y);
        acc0.z = fmaf(xv0.z, w2.z, acc0.z); acc0.w = fmaf(xv0.z, w2.w, acc0.w);
        acc0.x = fmaf(xv0.w, w3.x, acc0.x); acc0.y = fmaf(xv0.w, w3.y, acc0.y);
        acc0.z = fmaf(xv0.w, w3.z, acc0.z); acc0.w = fmaf(xv0.w, w3.w, acc0.w);
        acc1.x = fmaf(xv1.x, w0.x, acc1.x); acc1.y = fmaf(xv1.x, w0.y, acc1.y);
        acc1.z = fmaf(xv1.x, w0.z, acc1.z); acc1.w = fmaf(xv1.x, w0.w, acc1.w);
        acc1.x = fmaf(xv1.y, w1.x, acc1.x); acc1.y = fmaf(xv1.y, w1.y, acc1.y);
        acc1.z = fmaf(xv1.y, w1.z, acc1.z); acc1.w = fmaf(xv1.y, w1.w, acc1.w);
        acc1.x = fmaf(xv1.z, w2.x, acc1.x); acc1.y = fmaf(xv1.z, w2.y, acc1.y);
        acc1.z = fmaf(xv1.z, w2.z, acc1.z); acc1.w = fmaf(xv1.z, w2.w, acc1.w);
        acc1.x = fmaf(xv1.w, w3.x, acc1.x); acc1.y = fmaf(xv1.w, w3.y, acc1.y);
        acc1.z = fmaf(xv1.w, w3.z, acc1.z); acc1.w = fmaf(xv1.w, w3.w, acc1.w);
    }

    if (w) {
        s_part[0][w - 1][l] = acc0;
        s_part[1][w - 1][l] = acc1;
    }
    __syncthreads();
    if (w == 0) {
        const float4 b4 = ((const float4*)bx)[l];
        acc0.x += b4.x; acc0.y += b4.y; acc0.z += b4.z; acc0.w += b4.w;
        acc1.x += b4.x; acc1.y += b4.y; acc1.z += b4.z; acc1.w += b4.w;
        #pragma unroll
        for (int q = 0; q < 7; q++) {
            const float4 q0 = s_part[0][q][l];
            const float4 q1 = s_part[1][q][l];
            acc0.x += q0.x; acc0.y += q0.y; acc0.z += q0.z; acc0.w += q0.w;
            acc1.x += q1.x; acc1.y += q1.y; acc1.z += q1.z; acc1.w += q1.w;
        }
        float4 t0, t1;
        t0.x = tanh_from_scaled(LOG2E2 * acc0.x);
        t0.y = tanh_from_scaled(LOG2E2 * acc0.y);
        t0.z = tanh_from_scaled(LOG2E2 * acc0.z);
        t0.w = tanh_from_scaled(LOG2E2 * acc0.w);
        t1.x = tanh_from_scaled(LOG2E2 * acc1.x);
        t1.y = tanh_from_scaled(LOG2E2 * acc1.y);
        t1.z = tanh_from_scaled(LOG2E2 * acc1.z);
        t1.w = tanh_from_scaled(LOG2E2 * acc1.w);
        ((float4*)(h + (size_t)row0 * DM))[l]       = t0;
        ((float4*)(h + (size_t)(row0 + 1) * DM))[l] = t1;
    }
}

// ---------------- Kernel 2: scores + softmax + weighted sum ----------------
// 512 blocks (2 i-rows each) x 1024 threads (16 waves) -> 2 blocks/CU, 32 waves/CU.
// Phase 1: thread = (j = tid&511, th = tid>>9 -> t-half); both rows per thread.
//   Per d-pair: 1 ds_read_b128 broadcast (4 EA) + 1 coalesced dwordx2 (EB pair)
//   + pair-merged rcp (1 rcp per row per pair).
__global__ __launch_bounds__(1024) void attn_k(
    const int*   __restrict__ mask,  // [B, N, N]
    const float* __restrict__ wv,    // [DM]
    const float* __restrict__ EA,    // [B*N, DM]
    const float2* __restrict__ EB2,  // [B][128][SEQ]
    const float* __restrict__ h,     // [B, N, DM]
    float* __restrict__ out,         // [B, N, DM]
    float* __restrict__ attn_out)    // [B, N, N]
{
    const int b   = blockIdx.x >> 8;         // 256 blocks per batch
    const int i0  = (blockIdx.x & 255) * 2;  // rows {i0, i0+1}
    const int tid = threadIdx.x;
    const int l   = tid & 63;
    const int j   = tid & 511;
    const int th  = __builtin_amdgcn_readfirstlane(tid >> 9);   // t-half 0/1

    __shared__ float4 s_ea[128];      // {eaA_d0, eaA_d1, eaB_d0, eaB_d1} : 2 KB
    __shared__ float  s_ap[2][SEQ];   // 4 KB upper-t-half partials
    __shared__ float  s_o[3][2][DM];  // 6 KB phase-3 partials
    __shared__ float  s_red[2][8];

    // stage EA pairs for both rows: t = tid (0..127)
    if (tid < 128) {
        const float2 ea_a = *(const float2*)(EA + (size_t)(b * SEQ + i0) * DM + 2*tid);
        const float2 ea_b = *(const float2*)(EA + (size_t)(b * SEQ + i0 + 1) * DM + 2*tid);
        s_ea[tid] = make_float4(ea_a.x, ea_a.y, ea_b.x, ea_b.y);
    }
    __syncthreads();

    // ---- phase 1: 64 d-pair iters per thread (t-half split) ----
    const float2* __restrict__ EBj = EB2 + (size_t)b * 128 * SEQ + j;
    const int t0 = th * 64;

    float aA = 0.f, aB = 0.f;
    #pragma unroll 8
    for (int t = t0; t < t0 + 64; t++) {
        const float2 eb = EBj[(size_t)t * SEQ];   // coalesced dwordx2 (L2)
        const float4 q  = s_ea[t];                // ds_read_b128 broadcast
        const float  w0 = wv[2*t];                // scalar stream
        const float  w1 = wv[2*t + 1];
        const float yA0 = fmaf(q.x, eb.x, 1.0f);
        const float yA1 = fmaf(q.y, eb.y, 1.0f);
        const float yB0 = fmaf(q.z, eb.x, 1.0f);
        const float yB1 = fmaf(q.w, eb.y, 1.0f);
        aA = fmaf(fmaf(w1, yA0, w0 * yA1), RCP(yA0 * yA1), aA);
        aB = fmaf(fmaf(w1, yB0, w0 * yB1), RCP(yB0 * yB1), aB);
    }

    if (th == 1) {
        s_ap[0][j] = aA;
        s_ap[1][j] = aB;
    }
    __syncthreads();

    // ---- phase 2 (lower t-half): masked softmax (score = const - 2a) ----
    const size_t mrowA = (size_t)b * SEQ * SEQ + (size_t)i0 * SEQ + j;
    float pA = 0.f, pB = 0.f;
    if (th == 0) {
        aA += s_ap[0][j];
        aB += s_ap[1][j];
        const int mA = mask[mrowA];
        const int mB = mask[mrowA + SEQ];
        pA = mA ? EXP2(-LOG2E2 * aA) : 0.f;
        pB = mB ? EXP2(-LOG2E2 * aB) : 0.f;

        float sA = pA, sB = pB;
        #pragma unroll
        for (int off = 32; off; off >>= 1) {
            sA += __shfl_xor(sA, off, 64);
            sB += __shfl_xor(sB, off, 64);
        }
        if (l == 0) {
            const int wj = tid >> 6;   // 0..7 for lower half
            s_red[0][wj] = sA;
            s_red[1][wj] = sB;
        }
    }
    __syncthreads();

    if (th == 0) {
        const float4 ra = ((const float4*)s_red[0])[0], rb = ((const float4*)s_red[0])[1];
        const float4 rc = ((const float4*)s_red[1])[0], rd = ((const float4*)s_red[1])[1];
        pA *= __fdividef(1.0f, (ra.x+ra.y+ra.z+ra.w) + (rb.x+rb.y+rb.z+rb.w));
        pB *= __fdividef(1.0f, (rc.x+rc.y+rc.z+rc.w) + (rd.x+rd.y+rd.z+rd.w));
        attn_out[mrowA]       = pA;
        attn_out[mrowA + SEQ] = pB;
    }
    __syncthreads();   // attn_out visible before phase 3

    // ---- phase 3: out[i_r,d] = sum_j p_r[j] * h[b,j,d] ----
    const int jq = __builtin_amdgcn_readfirstlane(tid >> 8);   // 0..3 -> 128-j slice
    const int d  = tid & 255;
    const float* __restrict__ hp  = h + (size_t)(b * SEQ + jq * 128) * DM + d;
    const float* __restrict__ ar0 = attn_out + (size_t)b * SEQ * SEQ
                                  + (size_t)i0 * SEQ + jq * 128;   // wave-uniform
    const float* __restrict__ ar1 = ar0 + SEQ;

    float c0 = 0.f, c1 = 0.f;
    #pragma unroll 4
    for (int q = 0; q < 32; q++) {
        const float4 P0 = *(const float4*)(ar0 + 4*q);   // uniform loads
        const float4 P1 = *(const float4*)(ar1 + 4*q);
        const float h0 = hp[(size_t)(4*q + 0) * DM];     // coalesced dword
        const float h1 = hp[(size_t)(4*q + 1) * DM];
        const float h2 = hp[(size_t)(4*q + 2) * DM];
        const float h3 = hp[(size_t)(4*q + 3) * DM];
        c0 = fmaf(P0.x, h0, fmaf(P0.y, h1, fmaf(P0.z, h2, fmaf(P0.w, h3, c0))));
        c1 = fmaf(P1.x, h0, fmaf(P1.y, h1, fmaf(P1.z, h2, fmaf(P1.w, h3, c1))));
    }

    if (jq > 0) {
        s_o[jq - 1][0][d] = c0;
        s_o[jq - 1][1][d] = c1;
    }
    __syncthreads();
    if (jq == 0) {
        float* __restrict__ op = out + (size_t)(b * SEQ + i0) * DM + d;
        op[0]  = c0 + s_o[0][0][d] + s_o[1][0][d] + s_o[2][0][d];
        op[DM] = c1 + s_o[0][1][d] + s_o[1][1][d] + s_o[2][1][d];
    }
}

extern "C" void kernel_launch(void* const* d_in, const int* in_sizes, int n_in,
                              void* d_out, int out_size, void* d_ws, size_t ws_size,
                              hipStream_t stream) {
    const float* x    = (const float*)d_in[0];
    const float* pos  = (const float*)d_in[1];
    const int*   mask = (const int*)  d_in[2];
    const float* Wx   = (const float*)d_in[3];
    const float* bx   = (const float*)d_in[4];
    const float* Wp   = (const float*)d_in[5];
    const float* bp   = (const float*)d_in[6];
    const float* wv   = (const float*)d_in[7];

    float* out      = (float*)d_out;                          // [B,N,DM]
    float* attn_out = (float*)d_out + (size_t)BATCH*SEQ*DM;   // [B,N,N]

    char*   ws  = (char*)d_ws;
    float*  h   = (float*)(ws);                               // 1 MB
    float*  EA  = (float*)(ws + (size_t)BATCH*SEQ*DM*4);      // 1 MB
    float2* EB2 = (float2*)(ws + 2*(size_t)BATCH*SEQ*DM*4);   // 1 MB

    prep_k<<<256 + (BATCH*SEQ)/2, 512, 0, stream>>>(pos, Wp, bp, x, Wx, bx, EA, EB2, h);
    attn_k<<<(BATCH*SEQ)/2, 1024, 0, stream>>>(mask, wv, EA, EB2, h, out, attn_out);
}

// Round 12
// 111.725 us; speedup vs baseline: 1.0825x; 1.0825x over previous
//
#include <hip/hip_runtime.h>
#include <hip/hip_bf16.h>
#include <math.h>

// Problem constants (from reference)
#define BATCH   2
#define SEQ     512     // N
#define DIN     512
#define DM      256     // d_model

#define LOG2E2  2.88539008177792681f   // 2*log2(e)

#if __has_builtin(__builtin_amdgcn_exp2f)
#define EXP2(x) __builtin_amdgcn_exp2f(x)
#else
#define EXP2(x) exp2f(x)
#endif
#if __has_builtin(__builtin_amdgcn_rcpf)
#define RCP(x) __builtin_amdgcn_rcpf(x)
#else
#define RCP(x) (1.0f / (x))
#endif

// tanh(t) with targ = 2*log2(e)*t: tanh = 1 - 2/(1 + exp2(targ)); overflow-safe.
__device__ __forceinline__ float tanh_from_scaled(float targ) {
    return fmaf(-2.0f, RCP(1.0f + EXP2(targ)), 1.0f);
}

// ---------------- Kernel 1: EB2 pairs + EA rows + h = tanh(x@Wx+bx) ----------------
// (unchanged from r10)
__global__ __launch_bounds__(512) void prep_k(
    const float* __restrict__ pos,  // [B, N, 4]
    const float* __restrict__ Wp,   // [4, DM]
    const float* __restrict__ bp,   // [DM]
    const float* __restrict__ x,    // [B*N, DIN]
    const float* __restrict__ Wx,   // [DIN, DM]
    const float* __restrict__ bx,   // [DM]
    float* __restrict__ EA,         // [B*N, DM]
    float2* __restrict__ EB2,       // [B][128][SEQ] float2
    float* __restrict__ h)          // [B*N, DM]
{
    const int tid = threadIdx.x;

    if (blockIdx.x < 256) {
        // ---- EB2 part: block = (b, tg); d-pair (2tg, 2tg+1); thread = j ----
        const int b  = blockIdx.x >> 7;
        const int tg = blockIdx.x & 127;
        const int d0 = 2 * tg, d1 = d0 + 1;

        const float4 p = ((const float4*)pos)[b * SEQ + tid];   // coalesced 16B
        const float P0 = fmaf(p.x, Wp[d0], fmaf(p.y, Wp[DM + d0],
                         fmaf(p.z, Wp[2*DM + d0], p.w * Wp[3*DM + d0])));
        const float P1 = fmaf(p.x, Wp[d1], fmaf(p.y, Wp[DM + d1],
                         fmaf(p.z, Wp[2*DM + d1], p.w * Wp[3*DM + d1])));
        EB2[((size_t)(b * 128 + tg)) * SEQ + tid] =
            make_float2(EXP2(-LOG2E2 * P0), EXP2(-LOG2E2 * P1));   // coalesced 8B
        return;
    }

    // ---- h + EA part: rows row0, row0+1 ----
    __shared__ float4 s_x[2][DIN/4];       // 4 KB
    __shared__ float4 s_part[2][7][64];    // 14 KB

    const int row0 = (blockIdx.x - 256) * 2;

    // EA (independent of h)
    {
        const int r2  = __builtin_amdgcn_readfirstlane(tid >> 8);   // 0/1
        const int d   = tid & 255;
        const int row = row0 + r2;
        const float4 p = ((const float4*)pos)[row];   // uniform -> s_load
        const float P = fmaf(p.x, Wp[d],
                        fmaf(p.y, Wp[DM + d],
                        fmaf(p.z, Wp[2*DM + d],
                             p.w * Wp[3*DM + d])));
        EA[(size_t)row * DM + d] = EXP2(LOG2E2 * (P + bp[d]));   // coalesced
    }

    // stage both x rows (coalesced float4)
    if (tid < 256) {
        const int r   = tid >> 7;
        const int idx = tid & 127;
        s_x[r][idx] = ((const float4*)(x + (size_t)(row0 + r) * DIN))[idx];
    }
    __syncthreads();

    const int w = tid >> 6;        // k-eighth 0..7
    const int l = tid & 63;        // lane -> cols 4l..4l+3

    float4 acc0 = make_float4(0.f, 0.f, 0.f, 0.f);
    float4 acc1 = make_float4(0.f, 0.f, 0.f, 0.f);
    const float* __restrict__ wxp = Wx + 4 * l;

    #pragma unroll 2
    for (int k4 = 0; k4 < 16; k4++) {
        const int kk = w * 16 + k4;
        const float4 xv0 = s_x[0][kk];                    // ds_read_b128 broadcast
        const float4 xv1 = s_x[1][kk];
        const float4 w0 = *(const float4*)(wxp + (size_t)(4*kk + 0) * DM);
        const float4 w1 = *(const float4*)(wxp + (size_t)(4*kk + 1) * DM);
        const float4 w2 = *(const float4*)(wxp + (size_t)(4*kk + 2) * DM);
        const float4 w3 = *(const float4*)(wxp + (size_t)(4*kk + 3) * DM);
        acc0.x = fmaf(xv0.x, w0.x, acc0.x); acc0.y = fmaf(xv0.x, w0.y, acc0.y);
        acc0.z = fmaf(xv0.x, w0.z, acc0.z); acc0.w = fmaf(xv0.x, w0.w, acc0.w);
        acc0.x = fmaf(xv0.y, w1.x, acc0.x); acc0.y = fmaf(xv0.y, w1.y, acc0.y);
        acc0.z = fmaf(xv0.y, w1.z, acc0.z); acc0.w = fmaf(xv0.y, w1.w, acc0.w);
        acc0.x = fmaf(xv0.z, w2.x, acc0.x); acc0.y = fmaf(xv0.z, w2.y, acc0.y);
        acc0.z = fmaf(xv0.z, w2.z, acc0.z); acc0.w = fmaf(xv0.z, w2.w, acc0.w);
        acc0.x = fmaf(xv0.w, w3.x, acc0.x); acc0.y = fmaf(xv0.w, w3.y, acc0.y);
        acc0.z = fmaf(xv0.w, w3.z, acc0.z); acc0.w = fmaf(xv0.w, w3.w, acc0.w);
        acc1.x = fmaf(xv1.x, w0.x, acc1.x); acc1.y = fmaf(xv1.x, w0.y, acc1.y);
        acc1.z = fmaf(xv1.x, w0.z, acc1.z); acc1.w = fmaf(xv1.x, w0.w, acc1.w);
        acc1.x = fmaf(xv1.y, w1.x, acc1.x); acc1.y = fmaf(xv1.y, w1.y, acc1.y);
        acc1.z = fmaf(xv1.y, w1.z, acc1.z); acc1.w = fmaf(xv1.y, w1.w, acc1.w);
        acc1.x = fmaf(xv1.z, w2.x, acc1.x); acc1.y = fmaf(xv1.z, w2.y, acc1.y);
        acc1.z = fmaf(xv1.z, w2.z, acc1.z); acc1.w = fmaf(xv1.z, w2.w, acc1.w);
        acc1.x = fmaf(xv1.w, w3.x, acc1.x); acc1.y = fmaf(xv1.w, w3.y, acc1.y);
        acc1.z = fmaf(xv1.w, w3.z, acc1.z); acc1.w = fmaf(xv1.w, w3.w, acc1.w);
    }

    if (w) {
        s_part[0][w - 1][l] = acc0;
        s_part[1][w - 1][l] = acc1;
    }
    __syncthreads();
    if (w == 0) {
        const float4 b4 = ((const float4*)bx)[l];
        acc0.x += b4.x; acc0.y += b4.y; acc0.z += b4.z; acc0.w += b4.w;
        acc1.x += b4.x; acc1.y += b4.y; acc1.z += b4.z; acc1.w += b4.w;
        #pragma unroll
        for (int q = 0; q < 7; q++) {
            const float4 q0 = s_part[0][q][l];
            const float4 q1 = s_part[1][q][l];
            acc0.x += q0.x; acc0.y += q0.y; acc0.z += q0.z; acc0.w += q0.w;
            acc1.x += q1.x; acc1.y += q1.y; acc1.z += q1.z; acc1.w += q1.w;
        }
        float4 t0, t1;
        t0.x = tanh_from_scaled(LOG2E2 * acc0.x);
        t0.y = tanh_from_scaled(LOG2E2 * acc0.y);
        t0.z = tanh_from_scaled(LOG2E2 * acc0.z);
        t0.w = tanh_from_scaled(LOG2E2 * acc0.w);
        t1.x = tanh_from_scaled(LOG2E2 * acc1.x);
        t1.y = tanh_from_scaled(LOG2E2 * acc1.y);
        t1.z = tanh_from_scaled(LOG2E2 * acc1.z);
        t1.w = tanh_from_scaled(LOG2E2 * acc1.w);
        ((float4*)(h + (size_t)row0 * DM))[l]       = t0;
        ((float4*)(h + (size_t)(row0 + 1) * DM))[l] = t1;
    }
}

// ---------------- Kernel 2: scores + softmax -> attn_out ----------------
// 512 blocks (2 i-rows each) x 512 threads (8 waves, 2 blocks/CU).
// thread = j (full d range, 128 pairs); one barrier after EA staging, one for softmax.
__global__ __launch_bounds__(512) void score_k(
    const int*   __restrict__ mask,  // [B, N, N]
    const float* __restrict__ wv,    // [DM]
    const float* __restrict__ EA,    // [B*N, DM]
    const float2* __restrict__ EB2,  // [B][128][SEQ]
    float* __restrict__ attn_out)    // [B, N, N]
{
    const int b   = blockIdx.x >> 8;         // 256 blocks per batch
    const int i0  = (blockIdx.x & 255) * 2;  // rows {i0, i0+1}
    const int tid = threadIdx.x;             // = j
    const int l   = tid & 63;

    __shared__ float4 s_ea[128];      // {eaA_d0, eaA_d1, eaB_d0, eaB_d1} : 2 KB
    __shared__ float  s_red[2][8];

    if (tid < 128) {
        const float2 ea_a = *(const float2*)(EA + (size_t)(b * SEQ + i0) * DM + 2*tid);
        const float2 ea_b = *(const float2*)(EA + (size_t)(b * SEQ + i0 + 1) * DM + 2*tid);
        s_ea[tid] = make_float4(ea_a.x, ea_a.y, ea_b.x, ea_b.y);
    }
    __syncthreads();

    // ---- phase 1: 128 d-pair iters; pair-merged rcp (1 per row per pair) ----
    const float2* __restrict__ EBj = EB2 + (size_t)b * 128 * SEQ + tid;

    float aA = 0.f, aB = 0.f;
    #pragma unroll 8
    for (int t = 0; t < 128; t++) {
        const float2 eb = EBj[(size_t)t * SEQ];   // coalesced dwordx2 (L2)
        const float4 q  = s_ea[t];                // ds_read_b128 broadcast
        const float  w0 = wv[2*t];                // scalar stream
        const float  w1 = wv[2*t + 1];
        const float yA0 = fmaf(q.x, eb.x, 1.0f);
        const float yA1 = fmaf(q.y, eb.y, 1.0f);
        const float yB0 = fmaf(q.z, eb.x, 1.0f);
        const float yB1 = fmaf(q.w, eb.y, 1.0f);
        aA = fmaf(fmaf(w1, yA0, w0 * yA1), RCP(yA0 * yA1), aA);
        aB = fmaf(fmaf(w1, yB0, w0 * yB1), RCP(yB0 * yB1), aB);
    }

    // ---- phase 2: masked softmax (score = const - 2a; shift-invariant) ----
    const size_t mrowA = (size_t)b * SEQ * SEQ + (size_t)i0 * SEQ + tid;
    const int mA = mask[mrowA];
    const int mB = mask[mrowA + SEQ];
    float pA = mA ? EXP2(-LOG2E2 * aA) : 0.f;
    float pB = mB ? EXP2(-LOG2E2 * aB) : 0.f;

    float sA = pA, sB = pB;
    #pragma unroll
    for (int off = 32; off; off >>= 1) {
        sA += __shfl_xor(sA, off, 64);
        sB += __shfl_xor(sB, off, 64);
    }
    const int w = tid >> 6;   // 0..7
    if (l == 0) { s_red[0][w] = sA; s_red[1][w] = sB; }
    __syncthreads();

    const float4 ra = ((const float4*)s_red[0])[0], rb = ((const float4*)s_red[0])[1];
    const float4 rc = ((const float4*)s_red[1])[0], rd = ((const float4*)s_red[1])[1];
    pA *= __fdividef(1.0f, (ra.x+ra.y+ra.z+ra.w) + (rb.x+rb.y+rb.z+rb.w));
    pB *= __fdividef(1.0f, (rc.x+rc.y+rc.z+rc.w) + (rd.x+rd.y+rd.z+rd.w));

    attn_out[mrowA]       = pA;
    attn_out[mrowA + SEQ] = pB;
}

// ---------------- Kernel 3: out[i,d] = sum_j attn[i,j] * h[b,j,d] ----------------
// 512 blocks (2 i-rows each) x 512 threads: thread = (d = tid&255, jh = tid>>8).
// p via wave-uniform s_load streams from attn_out (cross-kernel: coherent).
__global__ __launch_bounds__(512) void av_k(
    const float* __restrict__ attn_out,  // [B, N, N]
    const float* __restrict__ h,         // [B, N, DM]
    float* __restrict__ out)             // [B, N, DM]
{
    const int b   = blockIdx.x >> 8;
    const int i0  = (blockIdx.x & 255) * 2;
    const int tid = threadIdx.x;
    const int jh  = __builtin_amdgcn_readfirstlane(tid >> 8);   // 0/1 -> 256-j half
    const int d   = tid & 255;

    __shared__ float s_o[2][DM];   // 2 KB

    const float* __restrict__ hp  = h + (size_t)(b * SEQ + jh * 256) * DM + d;
    const float* __restrict__ ar0 = attn_out + (size_t)b * SEQ * SEQ
                                  + (size_t)i0 * SEQ + jh * 256;   // wave-uniform
    const float* __restrict__ ar1 = ar0 + SEQ;

    float c0 = 0.f, c1 = 0.f;
    #pragma unroll 4
    for (int q = 0; q < 64; q++) {
        const float4 P0 = *(const float4*)(ar0 + 4*q);   // s_load_dwordx4 streams
        const float4 P1 = *(const float4*)(ar1 + 4*q);
        const float h0 = hp[(size_t)(4*q + 0) * DM];     // coalesced dword
        const float h1 = hp[(size_t)(4*q + 1) * DM];
        const float h2 = hp[(size_t)(4*q + 2) * DM];
        const float h3 = hp[(size_t)(4*q + 3) * DM];
        c0 = fmaf(P0.x, h0, fmaf(P0.y, h1, fmaf(P0.z, h2, fmaf(P0.w, h3, c0))));
        c1 = fmaf(P1.x, h0, fmaf(P1.y, h1, fmaf(P1.z, h2, fmaf(P1.w, h3, c1))));
    }

    if (jh == 1) {
        s_o[0][d] = c0;
        s_o[1][d] = c1;
    }
    __syncthreads();
    if (jh == 0) {
        float* __restrict__ op = out + (size_t)(b * SEQ + i0) * DM + d;
        op[0]  = c0 + s_o[0][d];
        op[DM] = c1 + s_o[1][d];
    }
}

extern "C" void kernel_launch(void* const* d_in, const int* in_sizes, int n_in,
                              void* d_out, int out_size, void* d_ws, size_t ws_size,
                              hipStream_t stream) {
    const float* x    = (const float*)d_in[0];
    const float* pos  = (const float*)d_in[1];
    const int*   mask = (const int*)  d_in[2];
    const float* Wx   = (const float*)d_in[3];
    const float* bx   = (const float*)d_in[4];
    const float* Wp   = (const float*)d_in[5];
    const float* bp   = (const float*)d_in[6];
    const float* wv   = (const float*)d_in[7];

    float* out      = (float*)d_out;                          // [B,N,DM]
    float* attn_out = (float*)d_out + (size_t)BATCH*SEQ*DM;   // [B,N,N]

    char*   ws  = (char*)d_ws;
    float*  h   = (float*)(ws);                               // 1 MB
    float*  EA  = (float*)(ws + (size_t)BATCH*SEQ*DM*4);      // 1 MB
    float2* EB2 = (float2*)(ws + 2*(size_t)BATCH*SEQ*DM*4);   // 1 MB

    prep_k <<<256 + (BATCH*SEQ)/2, 512, 0, stream>>>(pos, Wp, bp, x, Wx, bx, EA, EB2, h);
    score_k<<<(BATCH*SEQ)/2, 512, 0, stream>>>(mask, wv, EA, EB2, attn_out);
    av_k   <<<(BATCH*SEQ)/2, 512, 0, stream>>>(attn_out, h, out);
}